// Round 8
// baseline (104.864 us; speedup 1.0000x reference)
//
#include <hip/hip_runtime.h>
#include <hip/hip_bf16.h>

namespace {

constexpr int MM = 64;
constexpr int KK = 4096;
constexpr int NN = 11008;
constexpr int NZROW = NN / 8;        // 1376
constexpr int BCOL = 64;             // cols per block = 4 waves x 16
constexpr int KSPLIT = 8;
constexpr int KSEG = KK / KSPLIT;    // 512
constexpr int BK = 32;               // k per chunk (one MFMA K)
constexpr int NCH = KSEG / BK;       // 16 chunks per kseg
constexpr int GR = 4;                // chunks per granule (= 128 k = 1 scale group)
constexpr int NGR = NCH / GR;        // 4 granules
constexpr int NT = NN / BCOL;        // 172 col-tiles -> grid 1376
constexpr size_t WS_NEED = (size_t)KSPLIT * MM * NN * 4;   // 22.5 MB partials

typedef float f32x4 __attribute__((ext_vector_type(4)));
typedef short s16x8 __attribute__((ext_vector_type(8)));
typedef int   i32x4 __attribute__((ext_vector_type(4)));

__device__ __forceinline__ int pack_bf16(float a, float b) {
  union { __hip_bfloat162 h; int i; } u;
  u.h.x = __float2bfloat16(a);
  u.h.y = __float2bfloat16(b);
  return u.i;
}

// fallback path only: out[m][n] = bias[n], atomics on top
__global__ __launch_bounds__(256) void prep_kernel(
    const float* __restrict__ bias, float* __restrict__ out)
{
  const int i = blockIdx.x * 256 + threadIdx.x;
  out[i] = bias[i % NN];
}

// ws path: out = bias + sum of KSPLIT partials
__global__ __launch_bounds__(256) void reduce_kernel(
    const float* __restrict__ ws, const float* __restrict__ bias,
    float* __restrict__ out)
{
  const int i4 = (blockIdx.x * 256 + threadIdx.x) * 4;
  f32x4 acc = *(const f32x4*)(bias + (i4 % NN));
  #pragma unroll
  for (int s = 0; s < KSPLIT; ++s)
    acc += *(const f32x4*)(ws + (size_t)s * (MM * NN) + i4);
  *(f32x4*)(out + i4) = acc;
}

// R13: occupancy + conflict fix over R12 (54us, occ 15.8%, 1.06M bank
// conflicts). LDS cut 64KB -> 32KB (2 x 16KB double-buffered 128k
// granules, 1 LDS-only barrier per granule boundary), BCOL 128 -> 64 so
// grid = 1376 blocks -> 4 blocks/CU resident x 4 waves = 16 waves/CU
// (50% occ). qw ring deepened to 6 (cold-HBM latency covered per wave).
// Staging assignment redesigned so the LDS write lane-index == lane:
// wave wv stages rows wv*16+(lane&15), k-offset quad*8, per chunk cc ->
// fragment slot (cc*4+wv)*256 + lane*4. Both ds_write_b128 and
// ds_read_b128 are then the canonical conflict-free 16B/lane pattern
// (no swizzle). Staging global reads = 16 full 128B lines per instr.
// B path unchanged (one qweight dword = one MFMA B-fragment; exact 2^23
// dequant, single rounding -> absmax 0.125 unchanged).
template<bool ATOMIC>
__global__ __launch_bounds__(256, 4) void gptq_gemm_kernel(
    const float* __restrict__ x, const int* __restrict__ qw,
    const int* __restrict__ qz, const float* __restrict__ scales,
    float* __restrict__ out)
{
  __shared__ int As[2][4096];   // 2 x 16 KB granule buffers

  const int tid  = threadIdx.x;
  const int wave = tid >> 6;
  const int lane = tid & 63;
  const int c    = lane & 15;
  const int quad = lane >> 4;

  const int ks     = blockIdx.x & 7;
  const int nt     = blockIdx.x >> 3;
  const int n0     = nt * BCOL;
  const int kbase0 = ks * KSEG;
  const int grp0   = kbase0 >> 7;          // scale-group base = ks*4

  const int ncol = n0 + wave * 16 + c;     // this wave's single col-tile

  // B: qw row (kbase0/8 + quad), col ncol; chunk i advances 4 qw-rows
  const int* qwb = qw + ((size_t)(kbase0 >> 3) + quad) * NN + ncol;
  // A staging: wave stages rows wave*16 + c, k = kbase0 + g*128 + cc*32 + quad*8
  const float* xsb = x + (size_t)(wave * 16 + c) * KK + kbase0 + quad * 8;

  f32x4 acc[4];
  #pragma unroll
  for (int r = 0; r < 4; ++r) acc[r] = {0.f, 0.f, 0.f, 0.f};

  f32x4 S0[4], S1[4];    // staging regs for next granule (8 x 16B)
  int   pB[8];           // qweight ring, depth-6
  float pS[2];           // scale prefetch
  int   pZ[2];           // qzero prefetch
  float s0, C0;          // current-group dequant constants

  auto pfB = [&](int i) { pB[i & 7] = qwb[(size_t)i * 4 * NN]; };
  auto pfS = [&](int g) {
    const int sl = g & 1;
    pS[sl] = scales[(size_t)(grp0 + g) * NN + ncol];
    pZ[sl] = qz[(size_t)(grp0 + g) * NZROW + (ncol >> 3)];
  };
  auto setSC = [&](int g) {
    const int sl = g & 1;
    const int sh = (ncol & 7) * 4;
    s0 = pS[sl];
    C0 = __int_as_float(0x4B000000 + ((pZ[sl] >> sh) & 15) + 1);
  };
  auto dq8 = [&](int v) -> i32x4 {
    i32x4 p;
    p.x = pack_bf16(s0 * (__int_as_float(((v      ) & 15) | 0x4B000000) - C0),
                    s0 * (__int_as_float(((v >>  4) & 15) | 0x4B000000) - C0));
    p.y = pack_bf16(s0 * (__int_as_float(((v >>  8) & 15) | 0x4B000000) - C0),
                    s0 * (__int_as_float(((v >> 12) & 15) | 0x4B000000) - C0));
    p.z = pack_bf16(s0 * (__int_as_float(((v >> 16) & 15) | 0x4B000000) - C0),
                    s0 * (__int_as_float(((v >> 20) & 15) | 0x4B000000) - C0));
    p.w = pack_bf16(s0 * (__int_as_float(((v >> 24) & 15) | 0x4B000000) - C0),
                    s0 * (__int_as_float(((v >> 28) & 15) | 0x4B000000) - C0));
    return p;
  };
  auto stage_load = [&](int g) {
    const float* xp = xsb + g * 128;
    #pragma unroll
    for (int cc = 0; cc < 4; ++cc) {
      S0[cc] = *(const f32x4*)(xp + cc * 32);
      S1[cc] = *(const f32x4*)(xp + cc * 32 + 4);
    }
  };
  auto stage_write = [&](int g) {
    int* Ab = &As[g & 1][0];
    #pragma unroll
    for (int cc = 0; cc < 4; ++cc) {
      i32x4 pa;
      pa.x = pack_bf16(S0[cc].x, S0[cc].y);
      pa.y = pack_bf16(S0[cc].z, S0[cc].w);
      pa.z = pack_bf16(S1[cc].x, S1[cc].y);
      pa.w = pack_bf16(S1[cc].z, S1[cc].w);
      *(i32x4*)&Ab[(cc * 4 + wave) * 256 + lane * 4] = pa;
    }
  };

  // ---- prologue: S loads first, then qw ring (so the pack's vmcnt wait
  // on S leaves the 6 newer qw loads in flight) ----
  pfS(0);
  stage_load(0);
  pfB(0); pfB(1); pfB(2); pfB(3); pfB(4); pfB(5);
  stage_write(0);
  // LDS-only barrier: ds_writes drained, qw prefetch vmcnt stays in flight
  __asm__ volatile("s_waitcnt lgkmcnt(0)\n\ts_barrier" ::: "memory");
  setSC(0);
  pfS(1);

  #pragma unroll
  for (int g = 0; g < NGR; ++g) {
    if (g + 1 < NGR) stage_load(g + 1);   // 4 granule-chunks of latency cover

    #pragma unroll
    for (int cc = 0; cc < 4; ++cc) {
      const int i = g * 4 + cc;
      if (i + 6 < NCH) pfB(i + 6);        // deep qw prefetch

      union { i32x4 i4; s16x8 s8; } ub;
      ub.i4 = dq8(pB[i & 7]);

      const int* Ab = &As[g & 1][0];
      #pragma unroll
      for (int r = 0; r < 4; ++r) {
        const s16x8 af = *(const s16x8*)&Ab[(cc * 4 + r) * 256 + lane * 4];
        acc[r] = __builtin_amdgcn_mfma_f32_16x16x32_bf16(af, ub.s8, acc[r], 0, 0, 0);
      }
    }

    if (g + 1 < NGR) {
      // write next granule into buf^1: its last readers drained at the
      // previous barrier, so write-before-barrier is race-free (R7-proven)
      stage_write(g + 1);
      __asm__ volatile("s_waitcnt lgkmcnt(0)\n\ts_barrier" ::: "memory");
      setSC(g + 1);
      if (g + 2 < NGR) pfS(g + 2);
    }
  }

  // ---- epilogue: rows r*16 + quad*4 + j, col ncol ----
  if (ATOMIC) {
    #pragma unroll
    for (int r = 0; r < 4; ++r) {
      const f32x4 a = acc[r];
      float* op = out + (size_t)(r * 16 + quad * 4) * NN + ncol;
      atomicAdd(&op[0],      a.x);
      atomicAdd(&op[NN],     a.y);
      atomicAdd(&op[2 * NN], a.z);
      atomicAdd(&op[3 * NN], a.w);
    }
  } else {
    float* wsp = out + (size_t)ks * (MM * NN);
    #pragma unroll
    for (int r = 0; r < 4; ++r) {
      const f32x4 a = acc[r];
      float* op = wsp + (size_t)(r * 16 + quad * 4) * NN + ncol;
      op[0]      = a.x;
      op[NN]     = a.y;
      op[2 * NN] = a.z;
      op[3 * NN] = a.w;
    }
  }
}

} // namespace

extern "C" void kernel_launch(void* const* d_in, const int* in_sizes, int n_in,
                              void* d_out, int out_size, void* d_ws, size_t ws_size,
                              hipStream_t stream) {
  const float* x      = (const float*)d_in[0];
  const int*   qw     = (const int*)d_in[1];
  const int*   qz     = (const int*)d_in[2];
  const float* scales = (const float*)d_in[3];
  const float* bias   = (const float*)d_in[4];
  float* out = (float*)d_out;

  if (ws_size >= WS_NEED) {
    float* ws = (float*)d_ws;
    gptq_gemm_kernel<false><<<NT * KSPLIT, 256, 0, stream>>>(x, qw, qz, scales, ws);
    reduce_kernel<<<(MM * NN) / 1024, 256, 0, stream>>>(ws, bias, out);
  } else {
    prep_kernel<<<(MM * NN) / 256, 256, 0, stream>>>(bias, out);
    gptq_gemm_kernel<true><<<NT * KSPLIT, 256, 0, stream>>>(x, qw, qz, scales, out);
  }
}

// Round 9
// 100.766 us; speedup vs baseline: 1.0407x; 1.0407x over previous
//
#include <hip/hip_runtime.h>
#include <hip/hip_bf16.h>

namespace {

constexpr int MM = 64;
constexpr int KK = 4096;
constexpr int NN = 11008;
constexpr int NZROW = NN / 8;     // 1376
constexpr int BN = 128;           // cols per block tile
constexpr int KSPLIT = 16;        // R14: 8 -> 16 (grid 688 -> 1376, 4 blk/CU resident)
constexpr int KSEG = KK / KSPLIT; // 256
constexpr int NTILES = NN / BN;   // 86
constexpr int BK = 32;            // k per chunk (one MFMA K)
constexpr int NCH = KSEG / BK;    // 8 chunks
constexpr int RS = 20;            // LDS row stride in int32 (16 data + 4 pad, rows 16B aligned)
constexpr int ABUF = MM * RS;     // 1280 int32 per buffer
constexpr int BBUF = BN * RS;     // 2560 int32 per buffer
constexpr size_t WS_NEED = (size_t)KSPLIT * MM * NN * 4;  // 45 MB partials

typedef float f32x4 __attribute__((ext_vector_type(4)));
typedef float f32x2 __attribute__((ext_vector_type(2)));
typedef short s16x8 __attribute__((ext_vector_type(8)));
typedef int   i32x4 __attribute__((ext_vector_type(4)));
typedef int   i32x2 __attribute__((ext_vector_type(2)));

__device__ __forceinline__ int pack_bf16(float a, float b) {
  union { __hip_bfloat162 h; int i; } u;
  u.h.x = __float2bfloat16(a);
  u.h.y = __float2bfloat16(b);
  return u.i;
}

// fallback path only: out[m][n] = bias[n], atomics on top
__global__ __launch_bounds__(256) void prep_kernel(
    const float* __restrict__ bias, float* __restrict__ out)
{
  const int i = blockIdx.x * 256 + threadIdx.x;
  out[i] = bias[i % NN];
}

// ws path: out = bias + sum of KSPLIT partials
__global__ __launch_bounds__(256) void reduce_kernel(
    const float* __restrict__ ws, const float* __restrict__ bias,
    float* __restrict__ out)
{
  const int i4 = (blockIdx.x * 256 + threadIdx.x) * 4;
  f32x4 acc = *(const f32x4*)(bias + (i4 % NN));   // i4, NN multiples of 4
  #pragma unroll
  for (int s = 0; s < KSPLIT; ++s)
    acc += *(const f32x4*)(ws + (size_t)s * (MM * NN) + i4);
  *(f32x4*)(out + i4) = acc;
}

// R14 = the proven-best R6/baseline kernel (96.4 us artifact) with ONE
// targeted fix. In-flight-byte math: hiding ~900-cyc cold-HBM qw latency
// needs ~21 KB/CU outstanding; baseline had 2.7 blk/CU x 4 waves x
// depth-2 x 512 B ~= 11 KB -> qw-latency-starved. Now: KSPLIT=16 (grid
// 1376 -> 4 resident blk/CU, full launch-bounds occupancy) + qw ring
// depth 3 -> 16 waves/CU x 3 x 512 B ~= 24 KB in flight. Everything else
// (staging layout, LDS-only barrier with vmcnt in flight, exact 2^23
// dequant with single rounding, epilogue) is byte-identical to baseline.
template<bool ATOMIC>
__global__ __launch_bounds__(256, 4) void gptq_gemm_kernel(
    const float* __restrict__ x, const int* __restrict__ qw,
    const int* __restrict__ qz, const float* __restrict__ scales,
    float* __restrict__ out)
{
  __shared__ int As[2 * ABUF];   // 10.2 KB
  __shared__ int Bs[2 * BBUF];   // 20.5 KB

  const int tid  = threadIdx.x;
  const int wave = tid >> 6;
  const int lane = tid & 63;
  const int c    = lane & 15;
  const int quad = lane >> 4;

  const int ks     = blockIdx.x & 15;
  const int ntile  = blockIdx.x >> 4;
  const int n0     = ntile * BN;
  const int kbase0 = ks * KSEG;

  const int am   = tid >> 2;          // A staging row 0..63
  const int aseg = tid & 3;           // A staging 8-k unit 0..3
  const int bu   = tid & 3;           // B staging qw row offset 0..3
  const int cp   = tid >> 2;          // B staging col-pair 0..63
  const int Ncp  = n0 + 2 * cp;
  const int mrow = wave * 16 + quad * 4;

  const float* xrow = x + am * KK + aseg * 8;

  f32x4 acc[8];
  #pragma unroll
  for (int t = 0; t < 8; ++t) acc[t] = {0.f, 0.f, 0.f, 0.f};

  // rotating prefetch registers (indices fold after full unroll)
  f32x4 pA0[2], pA1[2];   // x, depth-1 (L2-warm across same-ks blocks)
  f32x2 pS[2];            // scales, depth-1 (L3-warm)
  int   pZ[2];            // qzeros, depth-1
  i32x2 pB[4];            // qweight, depth-3 (cold HBM stream)

  auto pfA = [&](int i) {
    const int sl = i & 1;
    const int kc = kbase0 + i * BK;
    pA0[sl] = *(const f32x4*)(xrow + kc);
    pA1[sl] = *(const f32x4*)(xrow + kc + 4);
    const int g = kc >> 7;
    pS[sl] = *(const f32x2*)(scales + g * NN + Ncp);
    pZ[sl] = qz[g * NZROW + (Ncp >> 3)];
  };
  auto pfB = [&](int i) {
    const int kc = kbase0 + i * BK;
    pB[i & 3] = *(const i32x2*)(qw + (size_t)((kc >> 3) + bu) * NN + Ncp);
  };

  pfB(0); pfB(1); pfB(2); pfA(0);

  #pragma unroll
  for (int i = 0; i < NCH; ++i) {
    const int sl = i & 1;
    if (i + 3 < NCH) pfB(i + 3);    // deep qw prefetch (depth 3)
    if (i + 1 < NCH) pfA(i + 1);    // x/scale/zero prefetch

    // ---- stage A: fp32 -> bf16 pairs ----
    int* Abuf = As + sl * ABUF;
    i32x4 pa;
    pa.x = pack_bf16(pA0[sl].x, pA0[sl].y);
    pa.y = pack_bf16(pA0[sl].z, pA0[sl].w);
    pa.z = pack_bf16(pA1[sl].x, pA1[sl].y);
    pa.w = pack_bf16(pA1[sl].z, pA1[sl].w);
    *(i32x4*)&Abuf[am * RS + aseg * 4] = pa;

    // ---- stage B: 2 adjacent cols x 8 k, exact dequant ----
    // qf = (nib | 0x4B000000) = 2^23 + q exactly; subtract C = 2^23+z+1
    // (Sterbenz-exact integer q-z-1); single rounding in s*d.
    int* Bbuf = Bs + sl * BBUF;
    const float s0 = pS[sl].x, s1 = pS[sl].y;
    const int sh0 = (Ncp & 7) * 4;
    const int z0  = (pZ[sl] >> sh0) & 15;
    const int z1  = (pZ[sl] >> (sh0 + 4)) & 15;
    const float C0 = (float)(0x800000 + z0 + 1);
    const float C1 = (float)(0x800000 + z1 + 1);
    const int v0 = pB[i & 3].x, v1 = pB[i & 3].y;
    i32x4 pb0, pb1;
    pb0.x = pack_bf16(s0 * (__int_as_float(((v0      ) & 15) | 0x4B000000) - C0),
                      s0 * (__int_as_float(((v0 >>  4) & 15) | 0x4B000000) - C0));
    pb0.y = pack_bf16(s0 * (__int_as_float(((v0 >>  8) & 15) | 0x4B000000) - C0),
                      s0 * (__int_as_float(((v0 >> 12) & 15) | 0x4B000000) - C0));
    pb0.z = pack_bf16(s0 * (__int_as_float(((v0 >> 16) & 15) | 0x4B000000) - C0),
                      s0 * (__int_as_float(((v0 >> 20) & 15) | 0x4B000000) - C0));
    pb0.w = pack_bf16(s0 * (__int_as_float(((v0 >> 24) & 15) | 0x4B000000) - C0),
                      s0 * (__int_as_float(((v0 >> 28) & 15) | 0x4B000000) - C0));
    pb1.x = pack_bf16(s1 * (__int_as_float(((v1      ) & 15) | 0x4B000000) - C1),
                      s1 * (__int_as_float(((v1 >>  4) & 15) | 0x4B000000) - C1));
    pb1.y = pack_bf16(s1 * (__int_as_float(((v1 >>  8) & 15) | 0x4B000000) - C1),
                      s1 * (__int_as_float(((v1 >> 12) & 15) | 0x4B000000) - C1));
    pb1.z = pack_bf16(s1 * (__int_as_float(((v1 >> 16) & 15) | 0x4B000000) - C1),
                      s1 * (__int_as_float(((v1 >> 20) & 15) | 0x4B000000) - C1));
    pb1.w = pack_bf16(s1 * (__int_as_float(((v1 >> 24) & 15) | 0x4B000000) - C1),
                      s1 * (__int_as_float(((v1 >> 28) & 15) | 0x4B000000) - C1));
    *(i32x4*)&Bbuf[(2 * cp    ) * RS + bu * 4] = pb0;
    *(i32x4*)&Bbuf[(2 * cp + 1) * RS + bu * 4] = pb1;

    // LDS-only barrier: leaves prefetch vmcnt in flight across it
    __asm__ volatile("s_waitcnt lgkmcnt(0)\n\ts_barrier" ::: "memory");

    // ---- 8 MFMAs from this buffer (dbuf: no trailing barrier needed) ----
    const s16x8 af = *(const s16x8*)&Abuf[(wave * 16 + c) * RS + quad * 4];
    #pragma unroll
    for (int t = 0; t < 8; ++t) {
      const s16x8 bfr = *(const s16x8*)&Bbuf[(t * 16 + c) * RS + quad * 4];
      acc[t] = __builtin_amdgcn_mfma_f32_16x16x32_bf16(af, bfr, acc[t], 0, 0, 0);
    }
  }

  // ---- epilogue ----
  if (ATOMIC) {
    #pragma unroll
    for (int t = 0; t < 8; ++t) {
      const int N = n0 + t * 16 + c;
      atomicAdd(&out[(mrow + 0) * NN + N], acc[t].x);
      atomicAdd(&out[(mrow + 1) * NN + N], acc[t].y);
      atomicAdd(&out[(mrow + 2) * NN + N], acc[t].z);
      atomicAdd(&out[(mrow + 3) * NN + N], acc[t].w);
    }
  } else {
    float* wsp = out + (size_t)ks * (MM * NN);
    #pragma unroll
    for (int t = 0; t < 8; ++t) {
      const int N = n0 + t * 16 + c;
      wsp[(mrow + 0) * NN + N] = acc[t].x;
      wsp[(mrow + 1) * NN + N] = acc[t].y;
      wsp[(mrow + 2) * NN + N] = acc[t].z;
      wsp[(mrow + 3) * NN + N] = acc[t].w;
    }
  }
}

} // namespace

extern "C" void kernel_launch(void* const* d_in, const int* in_sizes, int n_in,
                              void* d_out, int out_size, void* d_ws, size_t ws_size,
                              hipStream_t stream) {
  const float* x      = (const float*)d_in[0];
  const int*   qw     = (const int*)d_in[1];
  const int*   qz     = (const int*)d_in[2];
  const float* scales = (const float*)d_in[3];
  const float* bias   = (const float*)d_in[4];
  float* out = (float*)d_out;

  if (ws_size >= WS_NEED) {
    float* ws = (float*)d_ws;
    gptq_gemm_kernel<false><<<NTILES * KSPLIT, 256, 0, stream>>>(x, qw, qz, scales, ws);
    reduce_kernel<<<(MM * NN) / 1024, 256, 0, stream>>>(ws, bias, out);
  } else {
    prep_kernel<<<(MM * NN) / 256, 256, 0, stream>>>(bias, out);
    gptq_gemm_kernel<true><<<NTILES * KSPLIT, 256, 0, stream>>>(x, qw, qz, scales, out);
  }
}